// Round 16
// baseline (176.184 us; speedup 1.0000x reference)
//
#include <hip/hip_runtime.h>
#include <stdint.h>

// Problem constants
//   B=32, SQ=SK=512, DIM=512, H=8, HD=64, SCALE=0.125

typedef unsigned short u16;
typedef __attribute__((ext_vector_type(4))) float f32x4;
typedef __attribute__((ext_vector_type(8))) __bf16 bf16x8;
typedef __attribute__((ext_vector_type(4))) unsigned short u16x4;
typedef __attribute__((ext_vector_type(8))) unsigned short u16x8;
typedef __attribute__((ext_vector_type(4))) int i32x4;
typedef __attribute__((ext_vector_type(4))) _Float16 f16x4;
typedef __attribute__((ext_vector_type(8))) _Float16 f16x8;

#define MFMA16(a, b, c) __builtin_amdgcn_mfma_f32_16x16x32_bf16((a), (b), (c), 0, 0, 0)

__device__ __forceinline__ u16 f2bf(float f) {
  unsigned u = __float_as_uint(f);
  u += 0x7fffu + ((u >> 16) & 1u);   // RNE
  return (u16)(u >> 16);
}
__device__ __forceinline__ float bf2f(u16 h) {
  return __uint_as_float(((unsigned)h) << 16);
}

// async global->LDS, 16B per lane. LDS dest = wave-uniform base + lane*16
// (linear); swizzling is done on the GLOBAL source address (rule #21).
__device__ __forceinline__ void gl_lds16(const void* g, void* l) {
  __builtin_amdgcn_global_load_lds(
      (const __attribute__((address_space(1))) unsigned int*)g,
      (__attribute__((address_space(3))) unsigned int*)l, 16, 0, 0);
}

// ---------------------------------------------------------------------------
// K0: weight prep, FRAGMENT-PACKED layout. For each 16(n) x 32(k) MFMA
// fragment tile: Wt[mat][nc][kb][lane*8+j] = bf16(W[kb*32+g*8+j][nc*16+fr]),
// lane = g*16+fr. A wave's B-fragment load is then ONE contiguous 1KB
// segment. mat 3 handles Wo -> hi/lo split (same packing).
// ---------------------------------------------------------------------------
__global__ __launch_bounds__(256) void k_prep(
    const float* __restrict__ Wq, const float* __restrict__ Wk,
    const float* __restrict__ Wv, const float* __restrict__ Wo,
    u16* __restrict__ Wt, u16* __restrict__ WoHi, u16* __restrict__ WoLo) {
  int t = blockIdx.x * 256 + threadIdx.x;   // 0..131071
  int mat = t >> 15;                        // 0..3
  int r = t & 32767;                        // frag-slot within matrix
  int nc = r >> 10, kb = (r >> 6) & 15, lane = r & 63;
  int fr = lane & 15, g = lane >> 4;
  int n = nc * 16 + fr;
  int kbase = kb * 32 + g * 8;
  if (mat < 3) {
    const float* __restrict__ W = (mat == 0) ? Wq : (mat == 1) ? Wk : Wv;
    u16x8 o;
#pragma unroll
    for (int j = 0; j < 8; ++j)
      o[j] = f2bf(W[(size_t)(kbase + j) * 512 + n]);
    *(u16x8*)&Wt[(size_t)mat * 262144 + (size_t)r * 8] = o;
  } else {
    u16x8 oh, ol;
#pragma unroll
    for (int j = 0; j < 8; ++j) {
      float wo = Wo[(size_t)(kbase + j) * 512 + n];
      u16 hi = f2bf(wo);
      oh[j] = hi;
      ol[j] = f2bf(wo - bf2f(hi));
    }
    *(u16x8*)&WoHi[(size_t)r * 8] = oh;
    *(u16x8*)&WoLo[(size_t)r * 8] = ol;
  }
}

// ---------------------------------------------------------------------------
// K0c: X -> bf16 (RNE), one pass. Xb[mat][16384][512]. Pure BW (~150MB).
// ---------------------------------------------------------------------------
__global__ __launch_bounds__(256) void k_cvt(
    const float* __restrict__ Xq, const float* __restrict__ Xk,
    const float* __restrict__ Xv, u16* __restrict__ Xb) {
  const float* __restrict__ src =
      (blockIdx.y == 0) ? Xq : (blockIdx.y == 1) ? Xk : Xv;
  size_t i8 = ((size_t)blockIdx.x * 256 + threadIdx.x) * 8;
  f32x4 v0 = *(const f32x4*)&src[i8];
  f32x4 v1 = *(const f32x4*)&src[i8 + 4];
  u16x8 o;
#pragma unroll
  for (int e = 0; e < 4; ++e) {
    o[e]     = f2bf(v0[e]);
    o[e + 4] = f2bf(v1[e]);
  }
  *(u16x8*)&Xb[(size_t)blockIdx.y * 8388608 + i8] = o;
}

// ---------------------------------------------------------------------------
// K0b: fused mask+bias -> fp16. MB[b][sq][sk] = mask ? fp16(bias) : -60000.
// (launched AFTER k_proj: MBp aliases the tail of Xb)
// ---------------------------------------------------------------------------
__global__ __launch_bounds__(256) void k_mb(
    const int* __restrict__ mask, const float* __restrict__ bias,
    _Float16* __restrict__ MB) {
  size_t i8 = ((size_t)blockIdx.x * 256 + threadIdx.x) * 8;
  i32x4 m0 = *(const i32x4*)&mask[i8];
  i32x4 m1 = *(const i32x4*)&mask[i8 + 4];
  size_t bi = i8 & 262143;                    // idx % (512*512), bias broadcast over b
  f32x4 b0 = *(const f32x4*)&bias[bi];
  f32x4 b1 = *(const f32x4*)&bias[bi + 4];
  const _Float16 MASKED = (_Float16)(-60000.0f);
  f16x8 o;
#pragma unroll
  for (int e = 0; e < 4; ++e) {
    o[e]     = (m0[e] != 0) ? (_Float16)b0[e] : MASKED;
    o[e + 4] = (m1[e] != 0) ? (_Float16)b1[e] : MASKED;
  }
  *(f16x8*)&MB[i8] = o;
}

// ---------------------------------------------------------------------------
// K1: projections. C[16384x512] = Xb(bf16) @ W, per mat. 256 thr / 4 waves
// (2x2), tile 128x128, BK=64, grid (4,128,3)=1536. A staged bf16 via
// global_load_lds, 2-buf; both-sides swizzle (rule #21). B fragments from
// FRAG-PACKED Wt: one coalesced 1KB segment per load. (unchanged — passing)
// ---------------------------------------------------------------------------
__global__ __launch_bounds__(256, 4) void k_proj(
    const u16* __restrict__ Xb, const u16* __restrict__ Wt,
    u16* __restrict__ Qb, u16* __restrict__ Kb, u16* __restrict__ Vtb) {
  __shared__ __align__(16) u16 lAb[2][128][64];   // 32 KB
  const int mat = blockIdx.z;
  const u16* __restrict__ Ab = Xb + (size_t)mat * 8388608;
  const u16* __restrict__ Bf = Wt + (size_t)mat * 262144;
  const int tid = threadIdx.x, lane = tid & 63, wid = tid >> 6;   // 4 waves
  const int wm = wid >> 1, wn = wid & 1;       // wave grid 2 x 2
  const int m0 = blockIdx.y * 128, n0 = blockIdx.x * 128;
  const int fr = lane & 15, g = lane >> 4;

  const int sub = lane >> 3;                   // 0..7 == row&7 (rb mult of 8)
  const int xo = ((lane & 7) ^ sub) * 8;       // swizzled col (u16 elems)
  const int swr = (fr & 7) << 4;               // read-side byte XOR

  const int nc0 = (n0 >> 4) + wn * 4;
  const u16* __restrict__ Bq[4];
#pragma unroll
  for (int fn = 0; fn < 4; ++fn)
    Bq[fn] = Bf + (size_t)((nc0 + fn) * 16) * 512 + lane * 8;

  f32x4 acc[4][4] = {};

  // prologue: stage tile 0
#pragma unroll
  for (int p = 0; p < 4; ++p) {
    const int rb = p * 32 + wid * 8;
    gl_lds16(Ab + (size_t)(m0 + rb + sub) * 512 + xo, &lAb[0][rb][0]);
  }
  __syncthreads();

  for (int kt = 0; kt < 8; ++kt) {
    const int cur = kt & 1, nxt = cur ^ 1;
    const int k0 = kt * 64;
    // B fragments for this kt — coalesced 1KB loads, issued FIRST
    bf16x8 bB[2][4];
#pragma unroll
    for (int fn = 0; fn < 4; ++fn) {
      bB[0][fn] = *(const bf16x8*)(Bq[fn] + (size_t)(kt * 2) * 512);
      bB[1][fn] = *(const bf16x8*)(Bq[fn] + (size_t)(kt * 2 + 1) * 512);
    }
    // stage kt+1 (in flight across the compute phase)
    if (kt < 7) {
#pragma unroll
      for (int p = 0; p < 4; ++p) {
        const int rb = p * 32 + wid * 8;
        gl_lds16(Ab + (size_t)(m0 + rb + sub) * 512 + k0 + 64 + xo,
                 &lAb[nxt][rb][0]);
      }
    }
    // compute tile kt: 8 ds_read_b128 + 32 MFMA per wave
#pragma unroll
    for (int kc = 0; kc < 2; ++kc) {
#pragma unroll
      for (int fm = 0; fm < 4; ++fm) {
        const char* rowb = (const char*)&lAb[cur][wm * 64 + fm * 16 + fr][0];
        bf16x8 af = *(const bf16x8*)(rowb + ((kc * 64 + g * 16) ^ swr));
#pragma unroll
        for (int fn = 0; fn < 4; ++fn)
          acc[fm][fn] = MFMA16(af, bB[kc][fn], acc[fm][fn]);
      }
    }
    __syncthreads();   // drains stage prefetch + tile handoff (2-phase)
  }

  // epilogue (wave tile 64x64 at (wm*64, wn*64))
  if (mat < 2) {
    u16* __restrict__ Out = (mat == 0) ? Qb : Kb;
#pragma unroll
    for (int fm = 0; fm < 4; ++fm) {
#pragma unroll
      for (int fn = 0; fn < 4; ++fn) {
        int gn = n0 + wn * 64 + fn * 16 + fr;
        int hh = gn >> 6, hd = gn & 63;
#pragma unroll
        for (int r = 0; r < 4; ++r) {
          int gm = m0 + wm * 64 + fm * 16 + g * 4 + r;
          int b = gm >> 9, sq = gm & 511;
          Out[(size_t)((b * 8 + hh) * 512 + sq) * 64 + hd] = f2bf(acc[fm][fn][r]);
        }
      }
    }
  } else {
#pragma unroll
    for (int fm = 0; fm < 4; ++fm) {
      int gm0 = m0 + wm * 64 + fm * 16 + g * 4;
      int b = gm0 >> 9, sq0 = gm0 & 511;
#pragma unroll
      for (int fn = 0; fn < 4; ++fn) {
        int gn = n0 + wn * 64 + fn * 16 + fr;
        int hh = gn >> 6, hd = gn & 63;
        u16x4 pv;
        pv[0] = f2bf(acc[fm][fn][0]); pv[1] = f2bf(acc[fm][fn][1]);
        pv[2] = f2bf(acc[fm][fn][2]); pv[3] = f2bf(acc[fm][fn][3]);
        *(u16x4*)&Vtb[(size_t)((b * 8 + hh) * 64 + hd) * 512 + sq0] = pv;
      }
    }
  }
}

// ---------------------------------------------------------------------------
// K2: attention. OCCUPANCY ROUND: 8 waves x 32 q-rows = 256 q-rows/block,
// grid = 32b x 8h x 2qq = 512 (2 blocks/CU -> 16 waves/CU vs 10.5 before).
// Per-wave body = round-11/15 proven code VERBATIM (32 rows, 2 q-frags
// sharing K/V fragment reads). Staging split = round-13's bisect-proven
// geometry (waves 0-3 stage K 16 rows each, 4-7 stage V). LDS 48KB
// (K 2x8K + V 2x8K + P 8x2K). Epilogue writes bf16 hi/lo pair for k_out.
// ---------------------------------------------------------------------------
__global__ __launch_bounds__(512, 4) void k_attn(
    const u16* __restrict__ Qb, const u16* __restrict__ Kb, const u16* __restrict__ Vtb,
    const _Float16* __restrict__ MB,
    u16* __restrict__ Ohi, u16* __restrict__ Olo) {
  __shared__ __align__(16) u16 kbuf[2][64][64];   // 16KB
  __shared__ __align__(16) u16 vbuf[2][64][64];   // 16KB
  __shared__ __align__(16) u16 lP[8][16][64];     // 16KB
  const int tid = threadIdx.x, lane = tid & 63, w = tid >> 6;   // 8 waves
  const int orig = blockIdx.x;
  const int xcd = orig & 7, idx = orig >> 3;      // idx 0..63
  const int qq = idx & 1, h = (idx >> 1) & 7;     // q-half, head
  const int b = xcd + 8 * (idx >> 4);             // b slow-varying per XCD
  const int bh = b * 8 + h;
  const int fr = lane & 15, g = lane >> 4;
  const int sq0 = qq * 256 + w * 32;
  const int sw = (fr & 7) << 4;                   // byte XOR swizzle (read side)
  const u16* __restrict__ Qh = Qb + (size_t)bh * 32768;
  const u16* __restrict__ Kh = Kb + (size_t)bh * 32768;
  const u16* __restrict__ Vh = Vtb + (size_t)bh * 32768;
  const _Float16* __restrict__ MBr = MB + (size_t)b * 262144 + (size_t)(sq0 + fr) * 512;
  char* lProw = (char*)&lP[w][fr][0];

  const int sub = lane >> 3;                      // 0..7
  const int xo = ((lane & 7) ^ sub) * 8;          // swizzled col (elems)

  bf16x8 qf[2][2];
#pragma unroll
  for (int qfi = 0; qfi < 2; ++qfi)
#pragma unroll
    for (int kc = 0; kc < 2; ++kc)
      qf[qfi][kc] = *(const bf16x8*)&Qh[(size_t)(sq0 + qfi * 16 + fr) * 64 + kc * 32 + g * 8];

  f32x4 oacc[2][4] = {};
  float mrow[2] = {-1e30f, -1e30f}, lrow[2] = {0.f, 0.f};

  // prologue: stage tile 0 (waves 0-3: K 16-row strips, waves 4-7: V strips)
  if (w < 4) {
    const int rb = w * 16;
    const u16* gs = Kh + (size_t)(rb + sub) * 64 + xo;
    gl_lds16(gs, &kbuf[0][rb][0]);
    gl_lds16(gs + 8 * 64, &kbuf[0][rb + 8][0]);
  } else {
    const int rb = (w - 4) * 16;
    const u16* gs = Vh + (size_t)(rb + sub) * 512 + xo;
    gl_lds16(gs, &vbuf[0][rb][0]);
    gl_lds16(gs + 8 * 512, &vbuf[0][rb + 8][0]);
  }
  __syncthreads();

  int cur = 0;
  for (int kt = 0; kt < 8; ++kt) {
    const int sk0 = kt * 64;
    f16x4 mbv[2][4];
#pragma unroll
    for (int qfi = 0; qfi < 2; ++qfi)
#pragma unroll
      for (int fn = 0; fn < 4; ++fn)
        mbv[qfi][fn] = *(const f16x4*)&MBr[(size_t)qfi * 16 * 512 + sk0 + fn * 16 + g * 4];
    if (kt < 7) {
      const int nb = cur ^ 1, sk0n = sk0 + 64;
      if (w < 4) {
        const int rb = w * 16;
        const u16* gs = Kh + (size_t)(sk0n + rb + sub) * 64 + xo;
        gl_lds16(gs, &kbuf[nb][rb][0]);
        gl_lds16(gs + 8 * 64, &kbuf[nb][rb + 8][0]);
      } else {
        const int rb = (w - 4) * 16;
        const u16* gs = Vh + (size_t)(rb + sub) * 512 + sk0n + xo;
        gl_lds16(gs, &vbuf[nb][rb][0]);
        gl_lds16(gs + 8 * 512, &vbuf[nb][rb + 8][0]);
      }
    }
    const char* kcb = (const char*)kbuf[cur];
    const char* vcb = (const char*)vbuf[cur];
    f32x4 sacc[2][4] = {};
#pragma unroll
    for (int fn = 0; fn < 4; ++fn) {
      const int r = fn * 16 + fr;
      bf16x8 kf0 = *(const bf16x8*)(kcb + (size_t)r * 128 + ((0 * 64 + g * 16) ^ sw));
      bf16x8 kf1 = *(const bf16x8*)(kcb + (size_t)r * 128 + ((1 * 64 + g * 16) ^ sw));
      sacc[0][fn] = MFMA16(kf0, qf[0][0], sacc[0][fn]);
      sacc[0][fn] = MFMA16(kf1, qf[0][1], sacc[0][fn]);
      sacc[1][fn] = MFMA16(kf0, qf[1][0], sacc[1][fn]);
      sacc[1][fn] = MFMA16(kf1, qf[1][1], sacc[1][fn]);
    }
#pragma unroll
    for (int qfi = 0; qfi < 2; ++qfi)
#pragma unroll
      for (int fn = 0; fn < 4; ++fn)
#pragma unroll
        for (int r = 0; r < 4; ++r)
          sacc[qfi][fn][r] = sacc[qfi][fn][r] * 0.125f + (float)mbv[qfi][fn][r];

#pragma unroll
    for (int qfi = 0; qfi < 2; ++qfi) {
      float t0 = fmaxf(fmaxf(sacc[qfi][0][0], sacc[qfi][0][1]),
                       fmaxf(sacc[qfi][0][2], sacc[qfi][0][3]));
      float t1 = fmaxf(fmaxf(sacc[qfi][1][0], sacc[qfi][1][1]),
                       fmaxf(sacc[qfi][1][2], sacc[qfi][1][3]));
      float t2 = fmaxf(fmaxf(sacc[qfi][2][0], sacc[qfi][2][1]),
                       fmaxf(sacc[qfi][2][2], sacc[qfi][2][3]));
      float t3 = fmaxf(fmaxf(sacc[qfi][3][0], sacc[qfi][3][1]),
                       fmaxf(sacc[qfi][3][2], sacc[qfi][3][3]));
      float pm = fmaxf(fmaxf(t0, t1), fmaxf(t2, t3));
      pm = fmaxf(pm, __shfl_xor(pm, 16));
      pm = fmaxf(pm, __shfl_xor(pm, 32));
      if (!__all(pm - mrow[qfi] <= 8.0f)) {     // defer-max (T13)
        float mn = fmaxf(mrow[qfi], pm);
        float sfac = __expf(mrow[qfi] - mn);
        mrow[qfi] = mn;
        lrow[qfi] *= sfac;
#pragma unroll
        for (int r = 0; r < 4; ++r) {
          float sr = __shfl(sfac, g * 4 + r);
#pragma unroll
          for (int fnh = 0; fnh < 4; ++fnh)
            oacc[qfi][fnh][r] *= sr;
        }
      }
      float ps = 0.f;
#pragma unroll
      for (int fn = 0; fn < 4; ++fn) {
        float p0 = __expf(sacc[qfi][fn][0] - mrow[qfi]);
        float p1 = __expf(sacc[qfi][fn][1] - mrow[qfi]);
        float p2 = __expf(sacc[qfi][fn][2] - mrow[qfi]);
        float p3 = __expf(sacc[qfi][fn][3] - mrow[qfi]);
        ps += (p0 + p1) + (p2 + p3);
        u16x4 pw;
        pw[0] = f2bf(p0); pw[1] = f2bf(p1); pw[2] = f2bf(p2); pw[3] = f2bf(p3);
        *(u16x4*)(lProw + ((fn * 32 + g * 8) ^ sw)) = pw;
      }
      ps += __shfl_xor(ps, 16);
      ps += __shfl_xor(ps, 32);
      lrow[qfi] += ps;
      __builtin_amdgcn_wave_barrier();
#pragma unroll
      for (int kc = 0; kc < 2; ++kc) {
        bf16x8 pf = *(const bf16x8*)(lProw + ((kc * 64 + g * 16) ^ sw));
#pragma unroll
        for (int fnh = 0; fnh < 4; ++fnh) {
          const int vr = fnh * 16 + fr;
          bf16x8 vf = *(const bf16x8*)(vcb + (size_t)vr * 128 + ((kc * 64 + g * 16) ^ sw));
          oacc[qfi][fnh] = MFMA16(pf, vf, oacc[qfi][fnh]);
        }
      }
      __builtin_amdgcn_wave_barrier();
    }
    __syncthreads();
    cur ^= 1;
  }
  // epilogue: O / l -> bf16 hi/lo pair for k_out's gl_lds staging
#pragma unroll
  for (int qfi = 0; qfi < 2; ++qfi) {
#pragma unroll
    for (int r = 0; r < 4; ++r) {
      float lr = __shfl(lrow[qfi], g * 4 + r);
      float inv = 1.0f / lr;
      const int sq = sq0 + qfi * 16 + g * 4 + r;
      const size_t base = ((size_t)b * 512 + sq) * 512 + h * 64;
#pragma unroll
      for (int fnh = 0; fnh < 4; ++fnh) {
        float o = oacc[qfi][fnh][r] * inv;
        u16 oh = f2bf(o);
        Ohi[base + fnh * 16 + fr] = oh;
        Olo[base + fnh * 16 + fr] = f2bf(o - bf2f(oh));
      }
    }
  }
}

// ---------------------------------------------------------------------------
// K3: output projection, 2-term bf16 split: C = Oh@Wh + Oh@Wl + Ol@Wh + bo.
// k_proj clone: A = Ohi/Olo bf16 via global_load_lds, BK=64, 2-buf,
// both-sides swizzle; B = frag-packed WoHi/WoLo. 256 thr / 4 waves (1x4),
// tile 64x128, grid (4,256)=1024, LDS 32KB. (unchanged — passing)
// ---------------------------------------------------------------------------
__global__ __launch_bounds__(256, 4) void k_out(
    const u16* __restrict__ Ohi, const u16* __restrict__ Olo,
    const u16* __restrict__ WoHi, const u16* __restrict__ WoLo,
    const float* __restrict__ bo, float* __restrict__ out) {
  __shared__ __align__(16) u16 lAh[2][64][64];   // 16 KB
  __shared__ __align__(16) u16 lAl[2][64][64];   // 16 KB
  const int tid = threadIdx.x, lane = tid & 63, w = tid >> 6;   // 4 waves
  const int wn = w;                              // wave grid 1 x 4
  const int m0 = blockIdx.y * 64, n0 = blockIdx.x * 128;
  const int fr = lane & 15, g = lane >> 4;

  const int sub = lane >> 3;                     // 0..7 == row&7
  const int xo = ((lane & 7) ^ sub) * 8;         // swizzled col (u16 elems)
  const int swr = (fr & 7) << 4;                 // read-side byte XOR

  const int nc0 = (n0 >> 4) + wn * 2;
  const u16* __restrict__ Bhp[2];
  const u16* __restrict__ Blp[2];
#pragma unroll
  for (int fn = 0; fn < 2; ++fn) {
    size_t off = (size_t)((nc0 + fn) * 16) * 512 + lane * 8;
    Bhp[fn] = WoHi + off;
    Blp[fn] = WoLo + off;
  }

  f32x4 acc[4][2] = {};

  // prologue: stage tile 0 — wave w stages rows [w*16, w*16+16) of hi and lo
  {
    const int rb = w * 16;
    gl_lds16(Ohi + (size_t)(m0 + rb + sub) * 512 + xo,     &lAh[0][rb][0]);
    gl_lds16(Ohi + (size_t)(m0 + rb + 8 + sub) * 512 + xo, &lAh[0][rb + 8][0]);
    gl_lds16(Olo + (size_t)(m0 + rb + sub) * 512 + xo,     &lAl[0][rb][0]);
    gl_lds16(Olo + (size_t)(m0 + rb + 8 + sub) * 512 + xo, &lAl[0][rb + 8][0]);
  }
  __syncthreads();

  for (int kt = 0; kt < 8; ++kt) {
    const int cur = kt & 1, nxt = cur ^ 1;
    const int k0 = kt * 64;
    // B fragments (hi/lo) for this kt — coalesced 1KB loads, issued FIRST
    bf16x8 bh[2][2], bl[2][2];
#pragma unroll
    for (int kc = 0; kc < 2; ++kc)
#pragma unroll
      for (int fn = 0; fn < 2; ++fn) {
        bh[kc][fn] = *(const bf16x8*)(Bhp[fn] + (size_t)(kt * 2 + kc) * 512);
        bl[kc][fn] = *(const bf16x8*)(Blp[fn] + (size_t)(kt * 2 + kc) * 512);
      }
    // stage kt+1 (in flight across the compute phase)
    if (kt < 7) {
      const int rb = w * 16;
      gl_lds16(Ohi + (size_t)(m0 + rb + sub) * 512 + k0 + 64 + xo,     &lAh[nxt][rb][0]);
      gl_lds16(Ohi + (size_t)(m0 + rb + 8 + sub) * 512 + k0 + 64 + xo, &lAh[nxt][rb + 8][0]);
      gl_lds16(Olo + (size_t)(m0 + rb + sub) * 512 + k0 + 64 + xo,     &lAl[nxt][rb][0]);
      gl_lds16(Olo + (size_t)(m0 + rb + 8 + sub) * 512 + k0 + 64 + xo, &lAl[nxt][rb + 8][0]);
    }
    // compute tile kt: 16 ds_read_b128 + 48 MFMA per wave
#pragma unroll
    for (int kc = 0; kc < 2; ++kc) {
#pragma unroll
      for (int fm = 0; fm < 4; ++fm) {
        const char* rowh = (const char*)&lAh[cur][fm * 16 + fr][0];
        const char* rowl = (const char*)&lAl[cur][fm * 16 + fr][0];
        const int bc = (kc * 64 + g * 16) ^ swr;
        bf16x8 ah = *(const bf16x8*)(rowh + bc);
        bf16x8 al = *(const bf16x8*)(rowl + bc);
#pragma unroll
        for (int fn = 0; fn < 2; ++fn) {
          acc[fm][fn] = MFMA16(ah, bh[kc][fn], acc[fm][fn]);
          acc[fm][fn] = MFMA16(ah, bl[kc][fn], acc[fm][fn]);
          acc[fm][fn] = MFMA16(al, bh[kc][fn], acc[fm][fn]);
        }
      }
    }
    __syncthreads();   // drains stage prefetch + tile handoff (2-phase)
  }

  // epilogue
#pragma unroll
  for (int fm = 0; fm < 4; ++fm) {
#pragma unroll
    for (int fn = 0; fn < 2; ++fn) {
      int gn = n0 + wn * 32 + fn * 16 + fr;
      float bv = bo[gn];
#pragma unroll
      for (int r = 0; r < 4; ++r) {
        int gm = m0 + fm * 16 + g * 4 + r;
        out[(size_t)gm * 512 + gn] = acc[fm][fn][r] + bv;
      }
    }
  }
}

// ---------------------------------------------------------------------------
extern "C" void kernel_launch(void* const* d_in, const int* in_sizes, int n_in,
                              void* d_out, int out_size, void* d_ws, size_t ws_size,
                              hipStream_t stream) {
  (void)in_sizes; (void)n_in; (void)out_size; (void)ws_size;
  const float* query = (const float*)d_in[0];
  const float* key_t = (const float*)d_in[1];
  const float* value = (const float*)d_in[2];
  const int*   mask  = (const int*)d_in[3];
  const float* Wq    = (const float*)d_in[4];
  const float* Wk    = (const float*)d_in[5];
  const float* Wv    = (const float*)d_in[6];
  const float* Wo    = (const float*)d_in[7];
  const float* bo    = (const float*)d_in[8];
  const float* bias  = (const float*)d_in[9];
  float* out = (float*)d_out;

  char* p = (char*)d_ws;
  u16* Wt   = (u16*)p; p += (size_t)3 * 512 * 512 * 2;       // 1.5 MB
  u16* WoHi = (u16*)p; p += (size_t)512 * 512 * 2;           // 0.5 MB
  u16* WoLo = (u16*)p; p += (size_t)512 * 512 * 2;           // 0.5 MB
  u16* Qb   = (u16*)p; p += (size_t)32 * 8 * 512 * 64 * 2;   // 16.8 MB
  u16* Kb   = (u16*)p; p += (size_t)32 * 8 * 512 * 64 * 2;   // 16.8 MB
  u16* Vtb  = (u16*)p; p += (size_t)32 * 8 * 512 * 64 * 2;   // 16.8 MB
  // Region 3 (50.3 MB), time-multiplexed:
  //   phase 1 (k_cvt .. k_proj): Xb[3][16384][512] bf16 (50.3 MB)
  //   phase 2 (k_mb .. k_out):   Ohi (16.8) + Olo (16.8) + MBp (16.8)
  u16* Xb = (u16*)p;
  u16* Ohi = (u16*)p;
  u16* Olo = (u16*)(p + (size_t)16384 * 512 * 2);
  _Float16* MBp = (_Float16*)(p + (size_t)2 * 16384 * 512 * 2);
  // total ws: 103.3 MB

  k_prep<<<512, 256, 0, stream>>>(Wq, Wk, Wv, Wo, Wt, WoHi, WoLo);
  k_cvt<<<dim3(4096, 3), 256, 0, stream>>>(query, key_t, value, Xb);
  k_proj<<<dim3(4, 128, 3), 256, 0, stream>>>(Xb, Wt, Qb, Kb, Vtb);
  k_mb<<<4096, 256, 0, stream>>>(mask, bias, MBp);      // after k_proj: MBp aliases Xb tail
  k_attn<<<512, 512, 0, stream>>>(Qb, Kb, Vtb, MBp, Ohi, Olo);
  k_out<<<dim3(4, 256), 256, 0, stream>>>(Ohi, Olo, WoHi, WoLo, bo, out);
}

// Round 17
// 174.884 us; speedup vs baseline: 1.0074x; 1.0074x over previous
//
#include <hip/hip_runtime.h>
#include <stdint.h>

// Problem constants
//   B=32, SQ=SK=512, DIM=512, H=8, HD=64, SCALE=0.125

typedef unsigned short u16;
typedef __attribute__((ext_vector_type(4))) float f32x4;
typedef __attribute__((ext_vector_type(8))) __bf16 bf16x8;
typedef __attribute__((ext_vector_type(4))) unsigned short u16x4;
typedef __attribute__((ext_vector_type(8))) unsigned short u16x8;
typedef __attribute__((ext_vector_type(4))) int i32x4;
typedef __attribute__((ext_vector_type(4))) _Float16 f16x4;
typedef __attribute__((ext_vector_type(8))) _Float16 f16x8;

#define MFMA16(a, b, c) __builtin_amdgcn_mfma_f32_16x16x32_bf16((a), (b), (c), 0, 0, 0)
#define MFMA16H(a, b, c) __builtin_amdgcn_mfma_f32_16x16x32_f16((a), (b), (c), 0, 0, 0)

__device__ __forceinline__ u16 f2bf(float f) {
  unsigned u = __float_as_uint(f);
  u += 0x7fffu + ((u >> 16) & 1u);   // RNE
  return (u16)(u >> 16);
}
__device__ __forceinline__ float bf2f(u16 h) {
  return __uint_as_float(((unsigned)h) << 16);
}

// async global->LDS, 16B per lane. LDS dest = wave-uniform base + lane*16
// (linear); swizzling is done on the GLOBAL source address (rule #21).
__device__ __forceinline__ void gl_lds16(const void* g, void* l) {
  __builtin_amdgcn_global_load_lds(
      (const __attribute__((address_space(1))) unsigned int*)g,
      (__attribute__((address_space(3))) unsigned int*)l, 16, 0, 0);
}

// ---------------------------------------------------------------------------
// K0: weight prep, FRAGMENT-PACKED layout. For each 16(n) x 32(k) MFMA
// fragment tile: Wt[mat][nc][kb][lane*8+j] = bf16(W[kb*32+g*8+j][nc*16+fr]),
// lane = g*16+fr. A wave's B-fragment load is then ONE contiguous 1KB
// segment. mat 3 handles Wo -> hi/lo split (same packing).
// ---------------------------------------------------------------------------
__global__ __launch_bounds__(256) void k_prep(
    const float* __restrict__ Wq, const float* __restrict__ Wk,
    const float* __restrict__ Wv, const float* __restrict__ Wo,
    u16* __restrict__ Wt, u16* __restrict__ WoHi, u16* __restrict__ WoLo) {
  int t = blockIdx.x * 256 + threadIdx.x;   // 0..131071
  int mat = t >> 15;                        // 0..3
  int r = t & 32767;                        // frag-slot within matrix
  int nc = r >> 10, kb = (r >> 6) & 15, lane = r & 63;
  int fr = lane & 15, g = lane >> 4;
  int n = nc * 16 + fr;
  int kbase = kb * 32 + g * 8;
  if (mat < 3) {
    const float* __restrict__ W = (mat == 0) ? Wq : (mat == 1) ? Wk : Wv;
    u16x8 o;
#pragma unroll
    for (int j = 0; j < 8; ++j)
      o[j] = f2bf(W[(size_t)(kbase + j) * 512 + n]);
    *(u16x8*)&Wt[(size_t)mat * 262144 + (size_t)r * 8] = o;
  } else {
    u16x8 oh, ol;
#pragma unroll
    for (int j = 0; j < 8; ++j) {
      float wo = Wo[(size_t)(kbase + j) * 512 + n];
      u16 hi = f2bf(wo);
      oh[j] = hi;
      ol[j] = f2bf(wo - bf2f(hi));
    }
    *(u16x8*)&WoHi[(size_t)r * 8] = oh;
    *(u16x8*)&WoLo[(size_t)r * 8] = ol;
  }
}

// ---------------------------------------------------------------------------
// K0c: X -> bf16 (RNE), one pass. Xb[mat][16384][512]. Pure BW (~150MB).
// ---------------------------------------------------------------------------
__global__ __launch_bounds__(256) void k_cvt(
    const float* __restrict__ Xq, const float* __restrict__ Xk,
    const float* __restrict__ Xv, u16* __restrict__ Xb) {
  const float* __restrict__ src =
      (blockIdx.y == 0) ? Xq : (blockIdx.y == 1) ? Xk : Xv;
  size_t i8 = ((size_t)blockIdx.x * 256 + threadIdx.x) * 8;
  f32x4 v0 = *(const f32x4*)&src[i8];
  f32x4 v1 = *(const f32x4*)&src[i8 + 4];
  u16x8 o;
#pragma unroll
  for (int e = 0; e < 4; ++e) {
    o[e]     = f2bf(v0[e]);
    o[e + 4] = f2bf(v1[e]);
  }
  *(u16x8*)&Xb[(size_t)blockIdx.y * 8388608 + i8] = o;
}

// ---------------------------------------------------------------------------
// K0b: fused mask+bias -> fp16. MB[b][sq][sk] = mask ? fp16(bias) : -60000.
// (launched AFTER k_proj: MBp aliases the tail of Xb)
// ---------------------------------------------------------------------------
__global__ __launch_bounds__(256) void k_mb(
    const int* __restrict__ mask, const float* __restrict__ bias,
    _Float16* __restrict__ MB) {
  size_t i8 = ((size_t)blockIdx.x * 256 + threadIdx.x) * 8;
  i32x4 m0 = *(const i32x4*)&mask[i8];
  i32x4 m1 = *(const i32x4*)&mask[i8 + 4];
  size_t bi = i8 & 262143;                    // idx % (512*512), bias broadcast over b
  f32x4 b0 = *(const f32x4*)&bias[bi];
  f32x4 b1 = *(const f32x4*)&bias[bi + 4];
  const _Float16 MASKED = (_Float16)(-60000.0f);
  f16x8 o;
#pragma unroll
  for (int e = 0; e < 4; ++e) {
    o[e]     = (m0[e] != 0) ? (_Float16)b0[e] : MASKED;
    o[e + 4] = (m1[e] != 0) ? (_Float16)b1[e] : MASKED;
  }
  *(f16x8*)&MB[i8] = o;
}

// ---------------------------------------------------------------------------
// K1: projections. C[16384x512] = Xb(bf16) @ W, per mat. 256 thr / 4 waves
// (2x2), tile 128x128, BK=64, grid (4,128,3)=1536. A staged bf16 via
// global_load_lds, 2-buf; both-sides swizzle (rule #21). B fragments from
// FRAG-PACKED Wt. V epilogue now writes FP16 (RNE v_cvt, 1 VALU/elem) for
// k_attn's f16 PV pipeline; Q/K stay bf16.
// ---------------------------------------------------------------------------
__global__ __launch_bounds__(256, 4) void k_proj(
    const u16* __restrict__ Xb, const u16* __restrict__ Wt,
    u16* __restrict__ Qb, u16* __restrict__ Kb, u16* __restrict__ Vtb) {
  __shared__ __align__(16) u16 lAb[2][128][64];   // 32 KB
  const int mat = blockIdx.z;
  const u16* __restrict__ Ab = Xb + (size_t)mat * 8388608;
  const u16* __restrict__ Bf = Wt + (size_t)mat * 262144;
  const int tid = threadIdx.x, lane = tid & 63, wid = tid >> 6;   // 4 waves
  const int wm = wid >> 1, wn = wid & 1;       // wave grid 2 x 2
  const int m0 = blockIdx.y * 128, n0 = blockIdx.x * 128;
  const int fr = lane & 15, g = lane >> 4;

  const int sub = lane >> 3;                   // 0..7 == row&7 (rb mult of 8)
  const int xo = ((lane & 7) ^ sub) * 8;       // swizzled col (u16 elems)
  const int swr = (fr & 7) << 4;               // read-side byte XOR

  const int nc0 = (n0 >> 4) + wn * 4;
  const u16* __restrict__ Bq[4];
#pragma unroll
  for (int fn = 0; fn < 4; ++fn)
    Bq[fn] = Bf + (size_t)((nc0 + fn) * 16) * 512 + lane * 8;

  f32x4 acc[4][4] = {};

  // prologue: stage tile 0
#pragma unroll
  for (int p = 0; p < 4; ++p) {
    const int rb = p * 32 + wid * 8;
    gl_lds16(Ab + (size_t)(m0 + rb + sub) * 512 + xo, &lAb[0][rb][0]);
  }
  __syncthreads();

  for (int kt = 0; kt < 8; ++kt) {
    const int cur = kt & 1, nxt = cur ^ 1;
    const int k0 = kt * 64;
    // B fragments for this kt — coalesced 1KB loads, issued FIRST
    bf16x8 bB[2][4];
#pragma unroll
    for (int fn = 0; fn < 4; ++fn) {
      bB[0][fn] = *(const bf16x8*)(Bq[fn] + (size_t)(kt * 2) * 512);
      bB[1][fn] = *(const bf16x8*)(Bq[fn] + (size_t)(kt * 2 + 1) * 512);
    }
    // stage kt+1 (in flight across the compute phase)
    if (kt < 7) {
#pragma unroll
      for (int p = 0; p < 4; ++p) {
        const int rb = p * 32 + wid * 8;
        gl_lds16(Ab + (size_t)(m0 + rb + sub) * 512 + k0 + 64 + xo,
                 &lAb[nxt][rb][0]);
      }
    }
    // compute tile kt: 8 ds_read_b128 + 32 MFMA per wave
#pragma unroll
    for (int kc = 0; kc < 2; ++kc) {
#pragma unroll
      for (int fm = 0; fm < 4; ++fm) {
        const char* rowb = (const char*)&lAb[cur][wm * 64 + fm * 16 + fr][0];
        bf16x8 af = *(const bf16x8*)(rowb + ((kc * 64 + g * 16) ^ swr));
#pragma unroll
        for (int fn = 0; fn < 4; ++fn)
          acc[fm][fn] = MFMA16(af, bB[kc][fn], acc[fm][fn]);
      }
    }
    __syncthreads();   // drains stage prefetch + tile handoff (2-phase)
  }

  // epilogue (wave tile 64x64 at (wm*64, wn*64))
  if (mat < 2) {
    u16* __restrict__ Out = (mat == 0) ? Qb : Kb;
#pragma unroll
    for (int fm = 0; fm < 4; ++fm) {
#pragma unroll
      for (int fn = 0; fn < 4; ++fn) {
        int gn = n0 + wn * 64 + fn * 16 + fr;
        int hh = gn >> 6, hd = gn & 63;
#pragma unroll
        for (int r = 0; r < 4; ++r) {
          int gm = m0 + wm * 64 + fm * 16 + g * 4 + r;
          int b = gm >> 9, sq = gm & 511;
          Out[(size_t)((b * 8 + hh) * 512 + sq) * 64 + hd] = f2bf(acc[fm][fn][r]);
        }
      }
    }
  } else {
    // V: fp16 (RNE), transposed [b,h,hd,sk]
#pragma unroll
    for (int fm = 0; fm < 4; ++fm) {
      int gm0 = m0 + wm * 64 + fm * 16 + g * 4;
      int b = gm0 >> 9, sq0 = gm0 & 511;
#pragma unroll
      for (int fn = 0; fn < 4; ++fn) {
        int gn = n0 + wn * 64 + fn * 16 + fr;
        int hh = gn >> 6, hd = gn & 63;
        f16x4 pv;
        pv[0] = (_Float16)acc[fm][fn][0]; pv[1] = (_Float16)acc[fm][fn][1];
        pv[2] = (_Float16)acc[fm][fn][2]; pv[3] = (_Float16)acc[fm][fn][3];
        *(f16x4*)&Vtb[(size_t)((b * 8 + hh) * 64 + hd) * 512 + sq0] = pv;
      }
    }
  }
}

// ---------------------------------------------------------------------------
// K2: attention. Structure unchanged from round 16 (8 waves x 32 q-rows,
// grid 512, LDS 48KB). DATA-PATH CHANGE: P and V in FP16 (RNE scalar casts,
// 1 VALU vs f2bf's 4), PV via mfma_f32_16x16x32_f16 — same rate, MORE
// mantissa than bf16. QK (bf16), softmax, ps accumulation all identical.
// ---------------------------------------------------------------------------
__global__ __launch_bounds__(512, 4) void k_attn(
    const u16* __restrict__ Qb, const u16* __restrict__ Kb, const u16* __restrict__ Vtb,
    const _Float16* __restrict__ MB,
    u16* __restrict__ Ohi, u16* __restrict__ Olo) {
  __shared__ __align__(16) u16 kbuf[2][64][64];   // 16KB
  __shared__ __align__(16) u16 vbuf[2][64][64];   // 16KB (fp16 payload)
  __shared__ __align__(16) u16 lP[8][16][64];     // 16KB (fp16 payload)
  const int tid = threadIdx.x, lane = tid & 63, w = tid >> 6;   // 8 waves
  const int orig = blockIdx.x;
  const int xcd = orig & 7, idx = orig >> 3;      // idx 0..63
  const int qq = idx & 1, h = (idx >> 1) & 7;     // q-half, head
  const int b = xcd + 8 * (idx >> 4);             // b slow-varying per XCD
  const int bh = b * 8 + h;
  const int fr = lane & 15, g = lane >> 4;
  const int sq0 = qq * 256 + w * 32;
  const int sw = (fr & 7) << 4;                   // byte XOR swizzle (read side)
  const u16* __restrict__ Qh = Qb + (size_t)bh * 32768;
  const u16* __restrict__ Kh = Kb + (size_t)bh * 32768;
  const u16* __restrict__ Vh = Vtb + (size_t)bh * 32768;
  const _Float16* __restrict__ MBr = MB + (size_t)b * 262144 + (size_t)(sq0 + fr) * 512;
  char* lProw = (char*)&lP[w][fr][0];

  const int sub = lane >> 3;                      // 0..7
  const int xo = ((lane & 7) ^ sub) * 8;          // swizzled col (elems)

  bf16x8 qf[2][2];
#pragma unroll
  for (int qfi = 0; qfi < 2; ++qfi)
#pragma unroll
    for (int kc = 0; kc < 2; ++kc)
      qf[qfi][kc] = *(const bf16x8*)&Qh[(size_t)(sq0 + qfi * 16 + fr) * 64 + kc * 32 + g * 8];

  f32x4 oacc[2][4] = {};
  float mrow[2] = {-1e30f, -1e30f}, lrow[2] = {0.f, 0.f};

  // prologue: stage tile 0 (waves 0-3: K 16-row strips, waves 4-7: V strips)
  if (w < 4) {
    const int rb = w * 16;
    const u16* gs = Kh + (size_t)(rb + sub) * 64 + xo;
    gl_lds16(gs, &kbuf[0][rb][0]);
    gl_lds16(gs + 8 * 64, &kbuf[0][rb + 8][0]);
  } else {
    const int rb = (w - 4) * 16;
    const u16* gs = Vh + (size_t)(rb + sub) * 512 + xo;
    gl_lds16(gs, &vbuf[0][rb][0]);
    gl_lds16(gs + 8 * 512, &vbuf[0][rb + 8][0]);
  }
  __syncthreads();

  int cur = 0;
  for (int kt = 0; kt < 8; ++kt) {
    const int sk0 = kt * 64;
    f16x4 mbv[2][4];
#pragma unroll
    for (int qfi = 0; qfi < 2; ++qfi)
#pragma unroll
      for (int fn = 0; fn < 4; ++fn)
        mbv[qfi][fn] = *(const f16x4*)&MBr[(size_t)qfi * 16 * 512 + sk0 + fn * 16 + g * 4];
    if (kt < 7) {
      const int nb = cur ^ 1, sk0n = sk0 + 64;
      if (w < 4) {
        const int rb = w * 16;
        const u16* gs = Kh + (size_t)(sk0n + rb + sub) * 64 + xo;
        gl_lds16(gs, &kbuf[nb][rb][0]);
        gl_lds16(gs + 8 * 64, &kbuf[nb][rb + 8][0]);
      } else {
        const int rb = (w - 4) * 16;
        const u16* gs = Vh + (size_t)(rb + sub) * 512 + sk0n + xo;
        gl_lds16(gs, &vbuf[nb][rb][0]);
        gl_lds16(gs + 8 * 512, &vbuf[nb][rb + 8][0]);
      }
    }
    const char* kcb = (const char*)kbuf[cur];
    const char* vcb = (const char*)vbuf[cur];
    f32x4 sacc[2][4] = {};
#pragma unroll
    for (int fn = 0; fn < 4; ++fn) {
      const int r = fn * 16 + fr;
      bf16x8 kf0 = *(const bf16x8*)(kcb + (size_t)r * 128 + ((0 * 64 + g * 16) ^ sw));
      bf16x8 kf1 = *(const bf16x8*)(kcb + (size_t)r * 128 + ((1 * 64 + g * 16) ^ sw));
      sacc[0][fn] = MFMA16(kf0, qf[0][0], sacc[0][fn]);
      sacc[0][fn] = MFMA16(kf1, qf[0][1], sacc[0][fn]);
      sacc[1][fn] = MFMA16(kf0, qf[1][0], sacc[1][fn]);
      sacc[1][fn] = MFMA16(kf1, qf[1][1], sacc[1][fn]);
    }
#pragma unroll
    for (int qfi = 0; qfi < 2; ++qfi)
#pragma unroll
      for (int fn = 0; fn < 4; ++fn)
#pragma unroll
        for (int r = 0; r < 4; ++r)
          sacc[qfi][fn][r] = sacc[qfi][fn][r] * 0.125f + (float)mbv[qfi][fn][r];

#pragma unroll
    for (int qfi = 0; qfi < 2; ++qfi) {
      float t0 = fmaxf(fmaxf(sacc[qfi][0][0], sacc[qfi][0][1]),
                       fmaxf(sacc[qfi][0][2], sacc[qfi][0][3]));
      float t1 = fmaxf(fmaxf(sacc[qfi][1][0], sacc[qfi][1][1]),
                       fmaxf(sacc[qfi][1][2], sacc[qfi][1][3]));
      float t2 = fmaxf(fmaxf(sacc[qfi][2][0], sacc[qfi][2][1]),
                       fmaxf(sacc[qfi][2][2], sacc[qfi][2][3]));
      float t3 = fmaxf(fmaxf(sacc[qfi][3][0], sacc[qfi][3][1]),
                       fmaxf(sacc[qfi][3][2], sacc[qfi][3][3]));
      float pm = fmaxf(fmaxf(t0, t1), fmaxf(t2, t3));
      pm = fmaxf(pm, __shfl_xor(pm, 16));
      pm = fmaxf(pm, __shfl_xor(pm, 32));
      if (!__all(pm - mrow[qfi] <= 8.0f)) {     // defer-max (T13)
        float mn = fmaxf(mrow[qfi], pm);
        float sfac = __expf(mrow[qfi] - mn);
        mrow[qfi] = mn;
        lrow[qfi] *= sfac;
#pragma unroll
        for (int r = 0; r < 4; ++r) {
          float sr = __shfl(sfac, g * 4 + r);
#pragma unroll
          for (int fnh = 0; fnh < 4; ++fnh)
            oacc[qfi][fnh][r] *= sr;
        }
      }
      float ps = 0.f;
#pragma unroll
      for (int fn = 0; fn < 4; ++fn) {
        float p0 = __expf(sacc[qfi][fn][0] - mrow[qfi]);
        float p1 = __expf(sacc[qfi][fn][1] - mrow[qfi]);
        float p2 = __expf(sacc[qfi][fn][2] - mrow[qfi]);
        float p3 = __expf(sacc[qfi][fn][3] - mrow[qfi]);
        ps += (p0 + p1) + (p2 + p3);
        f16x4 pw;                                 // fp16 RNE, 1 VALU each
        pw[0] = (_Float16)p0; pw[1] = (_Float16)p1;
        pw[2] = (_Float16)p2; pw[3] = (_Float16)p3;
        *(f16x4*)(lProw + ((fn * 32 + g * 8) ^ sw)) = pw;
      }
      ps += __shfl_xor(ps, 16);
      ps += __shfl_xor(ps, 32);
      lrow[qfi] += ps;
      __builtin_amdgcn_wave_barrier();
#pragma unroll
      for (int kc = 0; kc < 2; ++kc) {
        f16x8 pf = *(const f16x8*)(lProw + ((kc * 64 + g * 16) ^ sw));
#pragma unroll
        for (int fnh = 0; fnh < 4; ++fnh) {
          const int vr = fnh * 16 + fr;
          f16x8 vf = *(const f16x8*)(vcb + (size_t)vr * 128 + ((kc * 64 + g * 16) ^ sw));
          oacc[qfi][fnh] = MFMA16H(pf, vf, oacc[qfi][fnh]);
        }
      }
      __builtin_amdgcn_wave_barrier();
    }
    __syncthreads();
    cur ^= 1;
  }
  // epilogue: O / l -> bf16 hi/lo pair for k_out's gl_lds staging
#pragma unroll
  for (int qfi = 0; qfi < 2; ++qfi) {
#pragma unroll
    for (int r = 0; r < 4; ++r) {
      float lr = __shfl(lrow[qfi], g * 4 + r);
      float inv = 1.0f / lr;
      const int sq = sq0 + qfi * 16 + g * 4 + r;
      const size_t base = ((size_t)b * 512 + sq) * 512 + h * 64;
#pragma unroll
      for (int fnh = 0; fnh < 4; ++fnh) {
        float o = oacc[qfi][fnh][r] * inv;
        u16 oh = f2bf(o);
        Ohi[base + fnh * 16 + fr] = oh;
        Olo[base + fnh * 16 + fr] = f2bf(o - bf2f(oh));
      }
    }
  }
}

// ---------------------------------------------------------------------------
// K3: output projection, 2-term bf16 split: C = Oh@Wh + Oh@Wl + Ol@Wh + bo.
// k_proj clone: A = Ohi/Olo bf16 via global_load_lds, BK=64, 2-buf,
// both-sides swizzle; B = frag-packed WoHi/WoLo. 256 thr / 4 waves (1x4),
// tile 64x128, grid (4,256)=1024, LDS 32KB. (unchanged — passing)
// ---------------------------------------------------------------------------
__global__ __launch_bounds__(256, 4) void k_out(
    const u16* __restrict__ Ohi, const u16* __restrict__ Olo,
    const u16* __restrict__ WoHi, const u16* __restrict__ WoLo,
    const float* __restrict__ bo, float* __restrict__ out) {
  __shared__ __align__(16) u16 lAh[2][64][64];   // 16 KB
  __shared__ __align__(16) u16 lAl[2][64][64];   // 16 KB
  const int tid = threadIdx.x, lane = tid & 63, w = tid >> 6;   // 4 waves
  const int wn = w;                              // wave grid 1 x 4
  const int m0 = blockIdx.y * 64, n0 = blockIdx.x * 128;
  const int fr = lane & 15, g = lane >> 4;

  const int sub = lane >> 3;                     // 0..7 == row&7
  const int xo = ((lane & 7) ^ sub) * 8;         // swizzled col (u16 elems)
  const int swr = (fr & 7) << 4;                 // read-side byte XOR

  const int nc0 = (n0 >> 4) + wn * 2;
  const u16* __restrict__ Bhp[2];
  const u16* __restrict__ Blp[2];
#pragma unroll
  for (int fn = 0; fn < 2; ++fn) {
    size_t off = (size_t)((nc0 + fn) * 16) * 512 + lane * 8;
    Bhp[fn] = WoHi + off;
    Blp[fn] = WoLo + off;
  }

  f32x4 acc[4][2] = {};

  // prologue: stage tile 0 — wave w stages rows [w*16, w*16+16) of hi and lo
  {
    const int rb = w * 16;
    gl_lds16(Ohi + (size_t)(m0 + rb + sub) * 512 + xo,     &lAh[0][rb][0]);
    gl_lds16(Ohi + (size_t)(m0 + rb + 8 + sub) * 512 + xo, &lAh[0][rb + 8][0]);
    gl_lds16(Olo + (size_t)(m0 + rb + sub) * 512 + xo,     &lAl[0][rb][0]);
    gl_lds16(Olo + (size_t)(m0 + rb + 8 + sub) * 512 + xo, &lAl[0][rb + 8][0]);
  }
  __syncthreads();

  for (int kt = 0; kt < 8; ++kt) {
    const int cur = kt & 1, nxt = cur ^ 1;
    const int k0 = kt * 64;
    // B fragments (hi/lo) for this kt — coalesced 1KB loads, issued FIRST
    bf16x8 bh[2][2], bl[2][2];
#pragma unroll
    for (int kc = 0; kc < 2; ++kc)
#pragma unroll
      for (int fn = 0; fn < 2; ++fn) {
        bh[kc][fn] = *(const bf16x8*)(Bhp[fn] + (size_t)(kt * 2 + kc) * 512);
        bl[kc][fn] = *(const bf16x8*)(Blp[fn] + (size_t)(kt * 2 + kc) * 512);
      }
    // stage kt+1 (in flight across the compute phase)
    if (kt < 7) {
      const int rb = w * 16;
      gl_lds16(Ohi + (size_t)(m0 + rb + sub) * 512 + k0 + 64 + xo,     &lAh[nxt][rb][0]);
      gl_lds16(Ohi + (size_t)(m0 + rb + 8 + sub) * 512 + k0 + 64 + xo, &lAh[nxt][rb + 8][0]);
      gl_lds16(Olo + (size_t)(m0 + rb + sub) * 512 + k0 + 64 + xo,     &lAl[nxt][rb][0]);
      gl_lds16(Olo + (size_t)(m0 + rb + 8 + sub) * 512 + k0 + 64 + xo, &lAl[nxt][rb + 8][0]);
    }
    // compute tile kt: 16 ds_read_b128 + 48 MFMA per wave
#pragma unroll
    for (int kc = 0; kc < 2; ++kc) {
#pragma unroll
      for (int fm = 0; fm < 4; ++fm) {
        const char* rowh = (const char*)&lAh[cur][fm * 16 + fr][0];
        const char* rowl = (const char*)&lAl[cur][fm * 16 + fr][0];
        const int bc = (kc * 64 + g * 16) ^ swr;
        bf16x8 ah = *(const bf16x8*)(rowh + bc);
        bf16x8 al = *(const bf16x8*)(rowl + bc);
#pragma unroll
        for (int fn = 0; fn < 2; ++fn) {
          acc[fm][fn] = MFMA16(ah, bh[kc][fn], acc[fm][fn]);
          acc[fm][fn] = MFMA16(ah, bl[kc][fn], acc[fm][fn]);
          acc[fm][fn] = MFMA16(al, bh[kc][fn], acc[fm][fn]);
        }
      }
    }
    __syncthreads();   // drains stage prefetch + tile handoff (2-phase)
  }

  // epilogue
#pragma unroll
  for (int fm = 0; fm < 4; ++fm) {
#pragma unroll
    for (int fn = 0; fn < 2; ++fn) {
      int gn = n0 + wn * 32 + fn * 16 + fr;
      float bv = bo[gn];
#pragma unroll
      for (int r = 0; r < 4; ++r) {
        int gm = m0 + fm * 16 + g * 4 + r;
        out[(size_t)gm * 512 + gn] = acc[fm][fn][r] + bv;
      }
    }
  }
}

// ---------------------------------------------------------------------------
extern "C" void kernel_launch(void* const* d_in, const int* in_sizes, int n_in,
                              void* d_out, int out_size, void* d_ws, size_t ws_size,
                              hipStream_t stream) {
  (void)in_sizes; (void)n_in; (void)out_size; (void)ws_size;
  const float* query = (const float*)d_in[0];
  const float* key_t = (const float*)d_in[1];
  const float* value = (const float*)d_in[2];
  const int*   mask  = (const int*)d_in[3];
  const float* Wq    = (const float*)d_in[4];
  const float* Wk    = (const float*)d_in[5];
  const float* Wv    = (const float*)d_in[6];
  const float* Wo    = (const float*)d_in[7];
  const float* bo    = (const float*)d_in[8];
  const float* bias  = (const float*)d_in[9];
  float* out = (float*)d_out;

  char* p = (char*)d_ws;
  u16* Wt   = (u16*)p; p += (size_t)3 * 512 * 512 * 2;       // 1.5 MB
  u16* WoHi = (u16*)p; p += (size_t)512 * 512 * 2;           // 0.5 MB
  u16* WoLo = (u16*)p; p += (size_t)512 * 512 * 2;           // 0.5 MB
  u16* Qb   = (u16*)p; p += (size_t)32 * 8 * 512 * 64 * 2;   // 16.8 MB
  u16* Kb   = (u16*)p; p += (size_t)32 * 8 * 512 * 64 * 2;   // 16.8 MB
  u16* Vtb  = (u16*)p; p += (size_t)32 * 8 * 512 * 64 * 2;   // 16.8 MB (fp16)
  // Region 3 (50.3 MB), time-multiplexed:
  //   phase 1 (k_cvt .. k_proj): Xb[3][16384][512] bf16 (50.3 MB)
  //   phase 2 (k_mb .. k_out):   Ohi (16.8) + Olo (16.8) + MBp (16.8)
  u16* Xb = (u16*)p;
  u16* Ohi = (u16*)p;
  u16* Olo = (u16*)(p + (size_t)16384 * 512 * 2);
  _Float16* MBp = (_Float16*)(p + (size_t)2 * 16384 * 512 * 2);
  // total ws: 103.3 MB

  k_prep<<<512, 256, 0, stream>>>(Wq, Wk, Wv, Wo, Wt, WoHi, WoLo);
  k_cvt<<<dim3(4096, 3), 256, 0, stream>>>(query, key_t, value, Xb);
  k_proj<<<dim3(4, 128, 3), 256, 0, stream>>>(Xb, Wt, Qb, Kb, Vtb);
  k_mb<<<4096, 256, 0, stream>>>(mask, bias, MBp);      // after k_proj: MBp aliases Xb tail
  k_attn<<<512, 512, 0, stream>>>(Qb, Kb, Vtb, MBp, Ohi, Olo);
  k_out<<<dim3(4, 256), 256, 0, stream>>>(Ohi, Olo, WoHi, WoLo, bo, out);
}